// Round 11
// baseline (38.503 us; speedup 1.0000x reference)
//
#include <hip/hip_runtime.h>
#include <hip/hip_fp16.h>
#include <math.h>

#define NNODE 512
#define NBATCH 4
#define NFEAT 12
#define QKD 128
#define NVD 128
#define EVD 32
#define CATD 160          // NVD + EVD
#define CATB 168          // catb LDS stride (bf16)
#define TRD 256
#define NCLS 5
#define NROWS 2048        // NBATCH * NNODE
#define EPSV 1e-5f
#define NSTATBUF 8        // split BN-stat atomic contention 8 ways
#define NCHUNK 4          // j-chunks (online-softmax loop)
#define JC 128            // j-chunk width
#define RPB 8             // query rows per attnTrans block
#define SSW 132           // sS row stride (f32)
#define KBW 136           // K/NV LDS row stride (ushort)

typedef float floatx4 __attribute__((ext_vector_type(4)));
typedef __bf16 bf16x8 __attribute__((ext_vector_type(8)));
typedef unsigned short ushort_t;
typedef ushort_t ushort8 __attribute__((ext_vector_type(8)));
typedef ushort_t ushort4v __attribute__((ext_vector_type(4)));

// f32 -> bf16 bits, round-to-nearest-even
static __device__ __forceinline__ ushort_t f2bf(float x) {
  unsigned int u = __float_as_uint(x);
  return (ushort_t)((u + 0x7fffu + ((u >> 16) & 1u)) >> 16);
}
static __device__ __forceinline__ bf16x8 pack8(ushort4v lo, ushort4v hi) {
  ushort8 u;
  u[0] = lo.x; u[1] = lo.y; u[2] = lo.z; u[3] = lo.w;
  u[4] = hi.x; u[5] = hi.y; u[6] = hi.z; u[7] = hi.w;
  return __builtin_bit_cast(bf16x8, u);
}
static __device__ __forceinline__ float h2f(ushort_t bits) {
  return __half2float(__ushort_as_half(bits));
}

// ---------------------------------------------------------------------------
// Kernel 0: pack {scale, edge} -> sme[b][i][j] (uint32).
//   low16  = fp16( coeff/(dist+1) ), 0 means MASKED (real scale >= 0.044)
//   high16 = fp16( edge )
// 12 MB fp32/int32 in -> 4 MB out; pure streaming, 2048 blocks x 256 thr.
// ---------------------------------------------------------------------------
__global__ __launch_bounds__(256) void prep_kernel(
    const float* __restrict__ dist, const int* __restrict__ mask,
    const float* __restrict__ edges, unsigned int* __restrict__ sme) {
  const int idx = (blockIdx.x * 256 + threadIdx.x) * 2;
  const float2 d2 = *(const float2*)(dist + idx);
  const int2   m2 = *(const int2*)(mask + idx);
  const float2 e2 = *(const float2*)(edges + idx);
  const float coeff = 0.0883883476483184f;  // 1/sqrt(128)
  const ushort_t s0 = m2.x ? (ushort_t)0
                           : __half_as_ushort(__float2half(coeff / (d2.x + 1.0f)));
  const ushort_t s1 = m2.y ? (ushort_t)0
                           : __half_as_ushort(__float2half(coeff / (d2.y + 1.0f)));
  const ushort_t e0 = __half_as_ushort(__float2half(e2.x));
  const ushort_t e1 = __half_as_ushort(__float2half(e2.y));
  uint2 w;
  w.x = ((unsigned int)e0 << 16) | s0;
  w.y = ((unsigned int)e1 << 16) | s1;
  *(uint2*)(sme + idx) = w;
}

// ---------------------------------------------------------------------------
// Kernel 1: projections -> bf16 Qb[row][d], Kb[row][d], NVT[b][d][j],
// Wtb (bf16 Wt). 256 blocks x 256 thr, 8 rows/block. Blocks 0..15 zero stats.
// ---------------------------------------------------------------------------
__global__ __launch_bounds__(256) void qkv_kernel(
    const float* __restrict__ nodes,
    const float* __restrict__ Wq, const float* __restrict__ bq,
    const float* __restrict__ Wk, const float* __restrict__ bk,
    const float* __restrict__ Wnv, const float* __restrict__ bnv,
    const float* __restrict__ Wt,
    ushort_t* __restrict__ Qb, ushort_t* __restrict__ Kb,
    ushort_t* __restrict__ NVT, ushort_t* __restrict__ Wtb,
    float* __restrict__ stats) {
  const int tid = threadIdx.x;
  const int blk = blockIdx.x;           // 0..255
  const int rowbase = blk * 8;
  const int b = rowbase >> 9;
  const int jloc = rowbase & (NNODE - 1);
  if (blk < 2 * NSTATBUF) stats[blk * 256 + tid] = 0.f;   // 16x256 = 4096
  {  // Wt -> bf16: 40960 elems, 160 per block
    const int base = blk * 160;
    if (tid < 160) Wtb[base + tid] = f2bf(Wt[base + tid]);
  }
  __shared__ float sn[RPB][NFEAT];
  if (tid < RPB * NFEAT) ((float*)sn)[tid] = nodes[(size_t)rowbase * NFEAT + tid];
  __syncthreads();

  // ---- Q/K: thread owns d = tid&127; rows (tid>>7)*4 .. +3 --------------
  {
    const int d  = tid & 127;
    const int rg = tid >> 7;
    float wq[NFEAT], wk[NFEAT];
#pragma unroll
    for (int k = 0; k < NFEAT; ++k) {
      wq[k] = Wq[d * NFEAT + k];
      wk[k] = Wk[d * NFEAT + k];
    }
    const float bqv = bq[d], bkv = bk[d];
#pragma unroll
    for (int rr = 0; rr < 4; ++rr) {
      const int rl = rg * 4 + rr;
      float aq = bqv, ak = bkv;
#pragma unroll
      for (int k = 0; k < NFEAT; ++k) {
        const float n = sn[rl][k];
        aq = fmaf(n, wq[k], aq);
        ak = fmaf(n, wk[k], ak);
      }
      Qb[(size_t)(rowbase + rl) * QKD + d] = f2bf(aq);
      Kb[(size_t)(rowbase + rl) * QKD + d] = f2bf(ak);
    }
  }
  // ---- NV^T: thread owns d = tid>>1, half = tid&1 (4 j each) ------------
  {
    const int d    = tid >> 1;
    const int half = tid & 1;
    float wnv[NFEAT];
#pragma unroll
    for (int k = 0; k < NFEAT; ++k) wnv[k] = Wnv[d * NFEAT + k];
    const float bnvv = bnv[d];
    ushort4v v;
#pragma unroll
    for (int e = 0; e < 4; ++e) {
      const int rl = half * 4 + e;
      float av = bnvv;
#pragma unroll
      for (int k = 0; k < NFEAT; ++k) av = fmaf(sn[rl][k], wnv[k], av);
      v[e] = f2bf(av);
    }
    *(ushort4v*)(NVT + (size_t)b * QKD * NNODE + (size_t)d * NNODE +
                 jloc + half * 4) = v;
  }
}

// ---------------------------------------------------------------------------
// Kernel 2: attnTrans — flash attention (online softmax over 4 chunks) fused
// with the tanh+transform MFMA and BN-stat atomics. Reads packed sme.
// 256 blocks (1/CU) x 512 thr (8 waves); block = 8 query rows x all 512 j.
// Fragment layout (16x16x32 bf16), verified R5. Garbage rows 8..15 contained.
// ---------------------------------------------------------------------------
__global__ __launch_bounds__(512) void attnTrans_kernel(
    const ushort_t* __restrict__ Qb, const ushort_t* __restrict__ Kb,
    const ushort_t* __restrict__ NVT,
    const unsigned int* __restrict__ sme,
    const float* __restrict__ Wev, const float* __restrict__ bev,
    const ushort_t* __restrict__ Wtb, const float* __restrict__ bt,
    float* __restrict__ vals, float* __restrict__ stats) {
  __shared__ ushort_t sKB[JC * KBW];          // 34.8 KB
  __shared__ ushort_t sNV[2][QKD * KBW];      // 69.6 KB (double-buffered)
  __shared__ __align__(16) float sS[16][SSW]; // 8.4 KB (scores -> w)
  __shared__ ushort_t catb[RPB * CATB];       // 2.7 KB
  __shared__ float sF[16], sF2[RPB], sSe[RPB], sSw[RPB];

  const int tid = threadIdx.x;
  const int bid = blockIdx.x;            // 0..255
  const int b   = bid >> 6;              // batch
  const int rg  = bid & 63;              // row group
  const int rowbase = b * NNODE + rg * RPB;

  const int lane = tid & 63;
  const int wv   = tid >> 6;             // wave 0..7
  const int col  = lane & 15;
  const int kg   = lane >> 4;

  if (tid < 16) sF[tid] = 0.f;           // rows 8..15 stay 0 forever

  // ---- Q A-fragments (rows constant across chunks) ----------------------
  bf16x8 aq[4];
  {
    const ushort_t* Qr = Qb + (size_t)(rowbase + (col & 7)) * QKD;
#pragma unroll
    for (int ks = 0; ks < 4; ++ks)
      aq[ks] = pack8(*(const ushort4v*)(Qr + ks * 32 + kg * 4),
                     *(const ushort4v*)(Qr + ks * 32 + 16 + kg * 4));
  }

  const int sd   = tid >> 2;             // staging row 0..127
  const int sseg = (tid & 3) * 32;       // 32-ushort segment
  const int jl   = wv * 16 + col;        // this thread's chunk-local j (QK^T)
  const int dpv  = wv * 16 + col;        // this thread's d column (PV)

  float m_run = -__builtin_inff(), l_run = 0.f, se_run = 0.f;  // row = wv
  floatx4 acc = {0.f, 0.f, 0.f, 0.f};    // PV accumulator (rows kg*4+r, col dpv)

  for (int c = 0; c < NCHUNK; ++c) {
    const int jbase = c * JC;
    // ---- prefetch packed scale/edge (score positions + softmax row) -----
    unsigned int sm[4];
#pragma unroll
    for (int r = 0; r < 4; ++r) {
      const size_t off =
          (size_t)(rowbase + ((kg * 4 + r) & 7)) * NNODE + jbase + jl;
      sm[r] = sme[off];
    }
    const unsigned int eu0 = sme[(size_t)(rowbase + wv) * NNODE + jbase + lane];
    const unsigned int eu1 =
        sme[(size_t)(rowbase + wv) * NNODE + jbase + 64 + lane];
    const float e0 = h2f((ushort_t)(eu0 >> 16));
    const float e1 = h2f((ushort_t)(eu1 >> 16));

    // ---- stage K chunk -> sKB, NV chunk -> sNV[c&1] ---------------------
    {
      const ushort8* ksrc =
          (const ushort8*)(Kb + (size_t)(b * NNODE + jbase + sd) * QKD + sseg);
      ushort8* kdst = (ushort8*)(sKB + sd * KBW + sseg);
#pragma unroll
      for (int t = 0; t < 4; ++t) kdst[t] = ksrc[t];
      const ushort8* nsrc = (const ushort8*)(NVT + (size_t)b * QKD * NNODE +
                                             (size_t)sd * NNODE + jbase + sseg);
      ushort8* ndst = (ushort8*)(sNV[c & 1] + sd * KBW + sseg);
#pragma unroll
      for (int t = 0; t < 4; ++t) ndst[t] = nsrc[t];
    }
    __syncthreads();

    // ---- QK^T: wave owns j-tile wv; 4 MFMAs -----------------------------
    {
      floatx4 sc = {0.f, 0.f, 0.f, 0.f};
      const ushort_t* kb = sKB + (size_t)jl * KBW;
#pragma unroll
      for (int ks = 0; ks < 4; ++ks) {
        const bf16x8 bfk = pack8(*(const ushort4v*)(kb + ks * 32 + kg * 4),
                                 *(const ushort4v*)(kb + ks * 32 + 16 + kg * 4));
        sc = __builtin_amdgcn_mfma_f32_16x16x32_bf16(aq[ks], bfk, sc, 0, 0, 0);
      }
#pragma unroll
      for (int r = 0; r < 4; ++r) {
        const ushort_t sb = (ushort_t)(sm[r] & 0xffffu);
        float s;
        if (sb) s = sc[r] * h2f(sb);     // scale = coeff/(dist+1)
        else    s = -__builtin_inff();   // masked
        sS[kg * 4 + r][jl] = s;
      }
    }
    __syncthreads();

    // ---- online softmax: wave wv owns row wv ----------------------------
    {
      const float v0 = sS[wv][lane];
      const float v1 = sS[wv][lane + 64];
      float mc = fmaxf(v0, v1);
#pragma unroll
      for (int s = 1; s < 64; s <<= 1) mc = fmaxf(mc, __shfl_xor(mc, s, 64));
      const float mn = fmaxf(m_run, mc);
      const float f = (m_run > -__builtin_inff()) ? __expf(m_run - mn) : 0.f;
      float w0 = 0.f, w1 = 0.f;
      if (mn > -__builtin_inff()) {      // wave-uniform
        w0 = __expf(v0 - mn);
        w1 = __expf(v1 - mn);
      }
      sS[wv][lane]      = w0;
      sS[wv][lane + 64] = w1;
      float lc = w0 + w1;
      float sec = fmaf(w0, e0, w1 * e1);
#pragma unroll
      for (int s = 1; s < 64; s <<= 1) {
        lc  += __shfl_xor(lc, s, 64);
        sec += __shfl_xor(sec, s, 64);
      }
      l_run  = l_run * f + lc;
      se_run = se_run * f + sec;
      m_run  = mn;
      if (lane == 0) sF[wv] = f;
    }
    __syncthreads();

    // ---- PV: rescale acc, then acc += w(16x128) @ NV(128x d-tile) -------
    {
      acc[0] *= sF[kg * 4 + 0];
      acc[1] *= sF[kg * 4 + 1];
      acc[2] *= sF[kg * 4 + 2];
      acc[3] *= sF[kg * 4 + 3];
      const ushort_t* nv = sNV[c & 1] + (size_t)dpv * KBW;
#pragma unroll
      for (int ks = 0; ks < 4; ++ks) {
        const float4 lo = *(const float4*)&sS[col][ks * 32 + kg * 4];
        const float4 hi = *(const float4*)&sS[col][ks * 32 + 16 + kg * 4];
        ushort8 u;
        u[0] = f2bf(lo.x); u[1] = f2bf(lo.y); u[2] = f2bf(lo.z); u[3] = f2bf(lo.w);
        u[4] = f2bf(hi.x); u[5] = f2bf(hi.y); u[6] = f2bf(hi.z); u[7] = f2bf(hi.w);
        const bf16x8 aw = __builtin_bit_cast(bf16x8, u);
        const bf16x8 bnv = pack8(*(const ushort4v*)(nv + ks * 32 + kg * 4),
                                 *(const ushort4v*)(nv + ks * 32 + 16 + kg * 4));
        acc = __builtin_amdgcn_mfma_f32_16x16x32_bf16(aw, bnv, acc, 0, 0, 0);
      }
    }
    // no loop-bottom barrier needed: next K-stage doesn't touch sNV[c&1]/sS,
    // next NV-stage targets the other buffer, and next sS writes are after
    // the next barrier (all waves have finished PV by then).
  }

  // ---- epilogue: finalize row stats -------------------------------------
  {
    const float inv = (l_run > 0.f) ? 1.f / l_run : 0.f;
    if (lane == 0) {
      sF2[wv] = inv;
      sSe[wv] = se_run * inv;
      sSw[wv] = (l_run > 0.f) ? 1.f : 0.f;
    }
  }
  __syncthreads();

  // ---- normalize + tanh -> catb (bf16) ----------------------------------
  if (kg < 2) {
#pragma unroll
    for (int r = 0; r < 4; ++r) {
      const int row = kg * 4 + r;
      catb[row * CATB + dpv] = f2bf(tanhf(acc[r] * sF2[row]));
    }
  }
  if (tid < RPB * EVD) {                 // 256 edge elems
    const int r = tid >> 5, de = tid & 31;
    catb[r * CATB + NVD + de] =
        f2bf(tanhf(fmaf(Wev[de], sSe[r], bev[de] * sSw[r])));
  }
  __syncthreads();

  // ---- transform: vals = catb @ Wtb^T + bt; BN stat atomics --------------
  {
    bf16x8 af[5];
    const ushort_t* cr = catb + (size_t)(col & 7) * CATB;
#pragma unroll
    for (int ks = 0; ks < 5; ++ks)
      af[ks] = pack8(*(const ushort4v*)(cr + ks * 32 + kg * 4),
                     *(const ushort4v*)(cr + ks * 32 + 16 + kg * 4));
    float* sbuf = stats + (size_t)(bid & (NSTATBUF - 1)) * 2 * TRD;
#pragma unroll
    for (int t = 0; t < 2; ++t) {        // 16 col-tiles / 8 waves
      const int o = (wv * 2 + t) * 16 + col;
      const ushort_t* wr = Wtb + (size_t)o * CATD;
      floatx4 a2 = {0.f, 0.f, 0.f, 0.f};
#pragma unroll
      for (int ks = 0; ks < 5; ++ks) {
        const bf16x8 bf = pack8(*(const ushort4v*)(wr + ks * 32 + kg * 4),
                                *(const ushort4v*)(wr + ks * 32 + 16 + kg * 4));
        a2 = __builtin_amdgcn_mfma_f32_16x16x32_bf16(af[ks], bf, a2, 0, 0, 0);
      }
      const float bto = bt[o];
      float s1 = 0.f, s2 = 0.f;
#pragma unroll
      for (int r = 0; r < 4; ++r) {
        const float v2 = a2[r] + bto;
        if (kg < 2) {
          vals[(size_t)(rowbase + kg * 4 + r) * TRD + o] = v2;
          s1 += v2;
          s2 = fmaf(v2, v2, s2);
        }
      }
      s1 += __shfl_xor(s1, 16, 64); s2 += __shfl_xor(s2, 16, 64);
      s1 += __shfl_xor(s1, 32, 64); s2 += __shfl_xor(s2, 32, 64);
      if (kg == 0) {
        atomicAdd(&sbuf[o], s1);
        atomicAdd(&sbuf[TRD + o], s2);
      }
    }
  }
}

// ---------------------------------------------------------------------------
// Kernel 3: fused BN-fold + classifier. 512 blocks x 256 thr, 4 rows/block.
// ---------------------------------------------------------------------------
__global__ __launch_bounds__(256) void outbn_kernel(
    const float* __restrict__ vals, const float* __restrict__ stats,
    const float* __restrict__ gamma, const float* __restrict__ beta,
    const float* __restrict__ Wc, const float* __restrict__ bc,
    float* __restrict__ out) {
  __shared__ float sW[NCLS][TRD];
  __shared__ float sb[NCLS];
  __shared__ float red[4][NCLS];
  const int tid = threadIdx.x;
  const int o = tid;                   // 0..255
  float s1 = 0.f, s2 = 0.f;
#pragma unroll
  for (int k = 0; k < NSTATBUF; ++k) {
    s1 += stats[k * 2 * TRD + o];
    s2 += stats[k * 2 * TRD + TRD + o];
  }
  const float invN = 1.0f / (float)NROWS;
  const float mu  = s1 * invN;
  const float var = s2 * invN - mu * mu;
  const float inv = 1.0f / sqrtf(var + EPSV);
  const float g = gamma[o] * inv;
  const float bterm = beta[o] - mu * g;
  float v[NCLS];
#pragma unroll
  for (int c = 0; c < NCLS; ++c) {
    const float wc = Wc[c * TRD + o];
    sW[c][o] = wc * g;
    v[c] = wc * bterm;
  }
#pragma unroll
  for (int s = 1; s < 64; s <<= 1) {
#pragma unroll
    for (int c = 0; c < NCLS; ++c) v[c] += __shfl_xor(v[c], s, 64);
  }
  if ((tid & 63) == 0) {
#pragma unroll
    for (int c = 0; c < NCLS; ++c) red[tid >> 6][c] = v[c];
  }
  __syncthreads();
  if (tid < NCLS)
    sb[tid] = bc[tid] + red[0][tid] + red[1][tid] + red[2][tid] + red[3][tid];
  __syncthreads();

  const int lane = tid & 63;
  const int row = blockIdx.x * 4 + (tid >> 6);
  float vv[TRD / 64];
#pragma unroll
  for (int t = 0; t < TRD / 64; ++t)
    vv[t] = vals[(size_t)row * TRD + lane + 64 * t];
#pragma unroll
  for (int c = 0; c < NCLS; ++c) {
    float p = 0.f;
#pragma unroll
    for (int t = 0; t < TRD / 64; ++t)
      p = fmaf(vv[t], sW[c][lane + 64 * t], p);
#pragma unroll
    for (int s = 1; s < 64; s <<= 1) p += __shfl_xor(p, s, 64);
    if (lane == 0) out[(size_t)row * NCLS + c] = p + sb[c];
  }
}

// ---------------------------------------------------------------------------
extern "C" void kernel_launch(void* const* d_in, const int* in_sizes, int n_in,
                              void* d_out, int out_size, void* d_ws, size_t ws_size,
                              hipStream_t stream) {
  (void)in_sizes; (void)n_in; (void)out_size; (void)ws_size;
  const float* nodes = (const float*)d_in[0];
  const float* edges = (const float*)d_in[1];
  const float* dist  = (const float*)d_in[2];
  const int*   mask  = (const int*)d_in[3];
  const float* Wq  = (const float*)d_in[4];
  const float* bq  = (const float*)d_in[5];
  const float* Wk  = (const float*)d_in[6];
  const float* bk  = (const float*)d_in[7];
  const float* Wnv = (const float*)d_in[8];
  const float* bnv = (const float*)d_in[9];
  const float* Wev = (const float*)d_in[10];
  const float* bev = (const float*)d_in[11];
  const float* Wt  = (const float*)d_in[12];
  const float* bt  = (const float*)d_in[13];
  const float* gamma = (const float*)d_in[14];
  const float* beta  = (const float*)d_in[15];
  const float* Wc  = (const float*)d_in[16];
  const float* bc  = (const float*)d_in[17];

  char* w = (char*)d_ws;
  ushort_t* Qb  = (ushort_t*)w;                w += (size_t)NROWS * QKD * 2;
  ushort_t* Kb  = (ushort_t*)w;                w += (size_t)NROWS * QKD * 2;
  ushort_t* NVT = (ushort_t*)w;                w += (size_t)NBATCH * QKD * NNODE * 2;
  ushort_t* Wtb = (ushort_t*)w;                w += (size_t)TRD * CATD * 2;
  unsigned int* sme = (unsigned int*)w;        w += (size_t)NBATCH * NNODE * NNODE * 4;
  float* vals  = (float*)w;                    w += (size_t)NROWS * TRD * 4;
  float* stats = (float*)w;
  float* outp  = (float*)d_out;

  prep_kernel<<<(NBATCH * NNODE * NNODE) / 512, 256, 0, stream>>>(
      dist, mask, edges, sme);
  qkv_kernel<<<NROWS / RPB, 256, 0, stream>>>(nodes, Wq, bq, Wk, bk, Wnv, bnv,
                                              Wt, Qb, Kb, NVT, Wtb, stats);
  attnTrans_kernel<<<NROWS / RPB, 512, 0, stream>>>(
      Qb, Kb, NVT, sme, Wev, bev, Wtb, bt, vals, stats);
  outbn_kernel<<<NROWS / 4, 256, 0, stream>>>(vals, stats, gamma, beta,
                                              Wc, bc, outp);
}